// Round 19
// baseline (273.313 us; speedup 1.0000x reference)
//
#include <hip/hip_runtime.h>
#include <cstdint>
#include <cstddef>

// Problem constants (B,S,D,H) = (2,2048,2048,16), DH=128
#define Bq  2
#define Sq  2048
#define Dq  2048
#define Hq  16
#define DHq 128
#define E3q 6144   // 3*D

typedef __attribute__((ext_vector_type(8))) short s16x8;   // 8 bf16 (4 VGPRs)
typedef __attribute__((ext_vector_type(4))) float f32x4;   // MFMA accumulator

__device__ __forceinline__ unsigned short f2bf(float f){
  union { float f; unsigned u; } v; v.f = f;
  unsigned r = v.u + 0x7FFFu + ((v.u >> 16) & 1u);   // round-to-nearest-even
  return (unsigned short)(r >> 16);
}
__device__ __forceinline__ float bf2f(unsigned short b){
  union { unsigned u; float f; } v; v.u = ((unsigned)b) << 16;
  return v.f;
}
// pack two f32 -> two bf16 in one op (no builtin on gfx950; T12 recipe)
__device__ __forceinline__ unsigned cvtpk_bf16(float lo, float hi){
  unsigned r;
  asm("v_cvt_pk_bf16_f32 %0, %1, %2" : "=v"(r) : "v"(lo), "v"(hi));
  return r;
}

// async global->LDS, 16B per lane. LDS dest must be wave-uniform base + lane*16.
__device__ __forceinline__ void gload_lds16(const void* g, void* l){
  __builtin_amdgcn_global_load_lds(
      (const __attribute__((address_space(1))) void*)g,
      (__attribute__((address_space(3))) void*)l, 16, 0, 0);
}

// ------ fused fp32->bf16 converts + RoPE (cos,sin) table ------
__global__ __launch_bounds__(256) void k_convert3(const float* __restrict__ x,
                                                  const float* __restrict__ win,
                                                  const float* __restrict__ wout,
                                                  const float* __restrict__ out_w,
                                                  const float* __restrict__ rp,
                                                  unsigned short* __restrict__ xb,
                                                  unsigned short* __restrict__ wb,
                                                  unsigned short* __restrict__ woutb,
                                                  float2* __restrict__ rpcs){
  const int NX = (Bq*Sq*Dq)/4;
  const int NW = (E3q*Dq)/4;
  const int NO = (Dq*Dq)/4;
  const int NR = (Sq*64)/4;
  const int total = NX + NW + NO + NR;
  int stride = gridDim.x * blockDim.x;
  for (int i = blockIdx.x*blockDim.x + threadIdx.x; i < total; i += stride){
    if (i < NX + NW){
      const float* src; unsigned short* dst; int j;
      if (i < NX){ src = x; dst = xb; j = i; }
      else { src = win; dst = wb; j = i - NX; }
      float4 v = reinterpret_cast<const float4*>(src)[j];
      ushort4 o;
      o.x = f2bf(v.x); o.y = f2bf(v.y); o.z = f2bf(v.z); o.w = f2bf(v.w);
      reinterpret_cast<ushort4*>(dst)[j] = o;
    } else if (i < NX + NW + NO){
      int j = i - NX - NW;
      float4 v = reinterpret_cast<const float4*>(wout)[j];
      float4 w = reinterpret_cast<const float4*>(out_w)[j & 511];
      ushort4 o;
      o.x = f2bf(v.x*w.x); o.y = f2bf(v.y*w.y); o.z = f2bf(v.z*w.z); o.w = f2bf(v.w*w.w);
      reinterpret_cast<ushort4*>(woutb)[j] = o;
    } else {
      int j = i - NX - NW - NO;
      float4 a = reinterpret_cast<const float4*>(rp)[j];
      float sn0,cs0,sn1,cs1,sn2,cs2,sn3,cs3;
      sincosf(a.x,&sn0,&cs0); sincosf(a.y,&sn1,&cs1);
      sincosf(a.z,&sn2,&cs2); sincosf(a.w,&sn3,&cs3);
      float4 p0 = make_float4(cs0,sn0,cs1,sn1);
      float4 p1 = make_float4(cs2,sn2,cs3,sn3);
      reinterpret_cast<float4*>(rpcs)[j*2  ] = p0;
      reinterpret_cast<float4*>(rpcs)[j*2+1] = p1;
    }
  }
}

// ---------------- GEMM1 fused: 8-phase 128x384 (proven 108.8us loop)
// + direct-register RoPE/RMS/transpose epilogue (3 heads per tile).
__global__ __launch_bounds__(512, 1) void k_gemm1f(const unsigned short* __restrict__ A,
                                                   const unsigned short* __restrict__ Bt,
                                                   const float* __restrict__ bias,
                                                   const float2* __restrict__ rpcs,
                                                   const float* __restrict__ qk_w,
                                                   unsigned short* __restrict__ Qp,
                                                   unsigned short* __restrict__ Kp,
                                                   unsigned short* __restrict__ Vt){
  const int K = 2048;
  const int bid = blockIdx.x;
  const int xcd = bid & 7, u = bid >> 3;          // 512 blocks, 64 per XCD
  const int m0 = (xcd*4 + (u & 3)) * 128;         // 32 M-tiles, 4 per XCD
  const int n0 = (u >> 2) * 384;                  // 16 N-tiles, col-major in chunk

  const int tid = threadIdx.x;
  const int lane = tid & 63, w = tid >> 6, g = lane >> 4, c = lane & 15;
  const int wm = w >> 2, wn = w & 3;              // 2 x 4 waves

  __shared__ __align__(16) unsigned short L[65536];   // 128 KB

  const int srow = tid >> 2, spc = tid & 3;
  const int ssw = (spc ^ ((srow >> 1) & 3)) << 3;
  const unsigned short* aSrc  = A  + (size_t)(m0 + srow      )*K + ssw;
  const unsigned short* bSrc0 = Bt + (size_t)(n0 + srow      )*K + ssw;
  const unsigned short* bSrc1 = Bt + (size_t)(n0 + srow + 128)*K + ssw;
  const unsigned short* bSrc2 = Bt + (size_t)(n0 + srow + 256)*K + ssw;

  auto stA = [&](int t, int h){
    gload_lds16(aSrc + t*64 + h*32, &L[((t&1)*2 + h)*4096 + tid*8]);
  };
  auto stB = [&](int t, int h, int uu){
    const unsigned short* s = (uu==0) ? bSrc0 : (uu==1) ? bSrc1 : bSrc2;
    gload_lds16(s + t*64 + h*32, &L[16384 + ((t&1)*2 + h)*12288 + uu*4096 + tid*8]);
  };

  int aoff[4], boff[6];
#pragma unroll
  for (int mf=0; mf<4; ++mf){
    int row = wm*64 + mf*16 + c;
    aoff[mf] = row*32 + ((g ^ ((row>>1)&3)) << 3);
  }
#pragma unroll
  for (int nf=0; nf<6; ++nf){
    int row = wn*96 + nf*16 + c;
    boff[nf] = row*32 + ((g ^ ((row>>1)&3)) << 3);
  }

  f32x4 acc[4][6];
#pragma unroll
  for (int i=0;i<4;i++)
#pragma unroll
    for (int j=0;j<6;j++)
#pragma unroll
      for (int r=0;r<4;r++) acc[i][j][r] = 0.f;

  auto RDA = [&](int b, int h, s16x8* af){
    const int ab = (b*2 + h)*4096;
#pragma unroll
    for (int mf=0; mf<4; ++mf) af[mf] = *(const s16x8*)&L[ab + aoff[mf]];
  };
  auto RDB = [&](int b, int h, int nh, s16x8* bf){
    const int bb = 16384 + (b*2 + h)*12288;
#pragma unroll
    for (int j=0; j<3; ++j) bf[j] = *(const s16x8*)&L[bb + boff[nh*3 + j]];
  };
  auto MM = [&](s16x8* af, s16x8* bf, int nh){
    __builtin_amdgcn_s_setprio(1);
#pragma unroll
    for (int mf=0; mf<4; ++mf)
#pragma unroll
      for (int j=0; j<3; ++j)
        acc[mf][nh*3+j] = __builtin_amdgcn_mfma_f32_16x16x32_bf16(af[mf], bf[j], acc[mf][nh*3+j], 0,0,0);
    __builtin_amdgcn_s_setprio(0);
  };
  auto BAR = [&](){
    __builtin_amdgcn_sched_barrier(0);
    __builtin_amdgcn_s_barrier();
    __builtin_amdgcn_sched_barrier(0);
  };

  // prologue: tile0 (8 units) + tile1 k0 (4 units)
  stA(0,0); stB(0,0,0); stB(0,0,1); stB(0,0,2);
  stA(0,1); stB(0,1,0); stB(0,1,1); stB(0,1,2);
  stA(1,0); stB(1,0,0); stB(1,0,1); stB(1,0,2);
  asm volatile("s_waitcnt vmcnt(4)" ::: "memory");
  __builtin_amdgcn_s_barrier();

  for (int i=0; i<16; ++i){
    const int T0 = 2*i, T1 = 2*i + 1;
    const bool st = (i < 15);
    s16x8 af[4], bf[3];
    // P1
    RDA(0,0,af); RDB(0,0,0,bf);
    stA(T1,1); stB(T1,1,0);
    BAR(); MM(af,bf,0); BAR();
    // P2
    RDB(0,0,1,bf);
    stB(T1,1,1); stB(T1,1,2);
    BAR(); MM(af,bf,1); BAR();
    // P3
    RDA(0,1,af); RDB(0,1,0,bf);
    if (st){ stA(T0+2,0); stB(T0+2,0,0); }
    BAR(); MM(af,bf,0); BAR();
    // P4 + checkpoint
    RDB(0,1,1,bf);
    if (st){ stB(T0+2,0,1); stB(T0+2,0,2); }
    __builtin_amdgcn_sched_barrier(0);
    if (st) asm volatile("s_waitcnt vmcnt(4)" ::: "memory");
    else    asm volatile("s_waitcnt vmcnt(0)" ::: "memory");
    BAR(); MM(af,bf,1); BAR();
    // P5
    RDA(1,0,af); RDB(1,0,0,bf);
    if (st){ stA(T0+2,1); stB(T0+2,1,0); }
    BAR(); MM(af,bf,0); BAR();
    // P6
    RDB(1,0,1,bf);
    if (st){ stB(T0+2,1,1); stB(T0+2,1,2); }
    BAR(); MM(af,bf,1); BAR();
    // P7
    RDA(1,1,af); RDB(1,1,0,bf);
    if (st){ stA(T1+2,0); stB(T1+2,0,0); }
    BAR(); MM(af,bf,0); BAR();
    // P8 + checkpoint
    RDB(1,1,1,bf);
    if (st){ stB(T1+2,0,1); stB(T1+2,0,2); }
    __builtin_amdgcn_sched_barrier(0);
    if (st) asm volatile("s_waitcnt vmcnt(4)" ::: "memory");
    else    asm volatile("s_waitcnt vmcnt(0)" ::: "memory");
    BAR(); MM(af,bf,1); BAR();
  }

  // ================= fused epilogue (direct from registers) =================
  const int b  = m0 >> 11;                 // batch
  const int sb = m0 & 2047;                // token base
  const int LTS = 392;                     // padded bf16 row stride (384+8)
  const float QSCALE = 0.08838834764831845f * 1.4426950408889634f;
  const int hdA = (wn*96) >> 7;            // first head this wave touches

  // bias add
#pragma unroll
  for (int nf=0; nf<6; ++nf){
    const float bv = bias[n0 + wn*96 + nf*16 + c];
#pragma unroll
    for (int mf=0; mf<4; ++mf)
#pragma unroll
      for (int r=0; r<4; ++r) acc[mf][nf][r] += bv;
  }

  __syncthreads();   // main-loop LDS use finished; L free

  // ---- per-row partial sumsq split by head (sA: head hdA, sB: head hdA+1) ----
  float sA[4][4], sB[4][4];
#pragma unroll
  for (int mf=0;mf<4;mf++)
#pragma unroll
    for (int r=0;r<4;r++){ sA[mf][r] = 0.f; sB[mf][r] = 0.f; }
#pragma unroll
  for (int nf=0; nf<6; ++nf){
    const int hd_nf = (wn*96 + nf*16) >> 7;
    if (hd_nf == hdA){
#pragma unroll
      for (int mf=0;mf<4;mf++)
#pragma unroll
        for (int r=0;r<4;r++){ float v = acc[mf][nf][r]; sA[mf][r] += v*v; }
    } else {
#pragma unroll
      for (int mf=0;mf<4;mf++)
#pragma unroll
        for (int r=0;r<4;r++){ float v = acc[mf][nf][r]; sB[mf][r] += v*v; }
    }
  }
#pragma unroll
  for (int m=1;m<16;m<<=1)
#pragma unroll
    for (int mf=0;mf<4;mf++)
#pragma unroll
      for (int r=0;r<4;r++){
        sA[mf][r] += __shfl_xor(sA[mf][r], m);
        sB[mf][r] += __shfl_xor(sB[mf][r], m);
      }

  // ---- combine across waves: SS[row][hd], each head has 2 contributors ----
  float* SS = (float*)&L[50176];           // 384 floats, after the bf16 tile
  if (c == 0){
#pragma unroll
    for (int mf=0;mf<4;mf++)
#pragma unroll
      for (int r=0;r<4;r++){
        const int row = wm*64 + mf*16 + g*4 + r;
        if (wn == 0) SS[row*3 + 0] = sA[mf][r];
        else if (wn == 1) SS[row*3 + 1] = sB[mf][r];
        else if (wn == 2) SS[row*3 + 2] = sB[mf][r];
      }
  }
  __syncthreads();
  if (c == 0){
#pragma unroll
    for (int mf=0;mf<4;mf++)
#pragma unroll
      for (int r=0;r<4;r++){
        const int row = wm*64 + mf*16 + g*4 + r;
        if (wn == 1) SS[row*3 + 0] += sA[mf][r];
        else if (wn == 2) SS[row*3 + 1] += sA[mf][r];
        else if (wn == 3) SS[row*3 + 2] += sA[mf][r];
      }
  }
  __syncthreads();

  // ---- per-row rsqrt for the (up to) 2 heads this wave touches ----
  const int hdB = (hdA < 2) ? hdA + 1 : 2;
  float rA[4][4], rB[4][4];
#pragma unroll
  for (int mf=0;mf<4;mf++)
#pragma unroll
    for (int r=0;r<4;r++){
      const int row = wm*64 + mf*16 + g*4 + r;
      rA[mf][r] = rsqrtf(SS[row*3 + hdA]*(1.f/128.f) + 1e-6f);
      rB[mf][r] = rsqrtf(SS[row*3 + hdB]*(1.f/128.f) + 1e-6f);
    }
  __syncthreads();   // done with SS; L fully reusable as bf16 tile

  // ---- process + dump to LDS tile [128][LTS] (rope'd Q/K, raw V) ----
  float wq[6]; int pp[6];
#pragma unroll
  for (int nf=0;nf<6;nf++){
    const int cw = (wn*96 + nf*16 + c) & 127;   // n0 % 128 == 0
    wq[nf] = qk_w[cw];
    pp[nf] = cw >> 1;
  }
#pragma unroll
  for (int nf=0; nf<6; ++nf){
    const int colw = wn*96 + nf*16 + c;
    const int bt = (n0 + colw) >> 11;           // uniform per (wave,nf)
    const int hd_nf = colw >> 7;
    if (bt < 2){
#pragma unroll
      for (int mf=0;mf<4;mf++)
#pragma unroll
        for (int r=0;r<4;r++){
          const int row = wm*64 + mf*16 + g*4 + r;
          const float rs = (hd_nf == hdA) ? rA[mf][r] : rB[mf][r];
          const float sc = rs * ((bt==0) ? QSCALE : 1.f);
          float v  = acc[mf][nf][r];
          float pv = __shfl_xor(v, 1);
          float2 t = rpcs[(sb + row)*64 + pp[nf]];
          float rot = ((c&1)==0) ? (v*t.x - pv*t.y) : (pv*t.y + v*t.x);
          L[row*LTS + colw] = f2bf(rot * sc * wq[nf]);
        }
    } else {
#pragma unroll
      for (int mf=0;mf<4;mf++)
#pragma unroll
        for (int r=0;r<4;r++){
          const int row = wm*64 + mf*16 + g*4 + r;
          L[row*LTS + colw] = f2bf(acc[mf][nf][r]);
        }
    }
  }
  __syncthreads();

  // ---- per-head coalesced output writes ----
#pragma unroll
  for (int hd=0; hd<3; ++hd){
    const int base = n0 + hd*128;
    if (base < 4096){
      // Q or K head: row-major copy out
      const bool isQ = (base < 2048);
      const int bh = b*Hq + ((base & 2047) >> 7);
      const int rw = tid >> 2, part = tid & 3;
      unsigned short* dst = (isQ ? Qp : Kp) + ((size_t)bh*Sq + sb + rw)*DHq + part*32;
      const unsigned short* srcl = &L[rw*LTS + hd*128 + part*32];
#pragma unroll
      for (int i2=0;i2<4;i2++)
        *(s16x8*)&dst[i2*8] = *(const s16x8*)&srcl[i2*8];
    } else {
      // V head: column gather -> Vt[bh][dh][s]
      const int bh = b*Hq + ((base - 4096) >> 7);
      const int dh = tid & 127, sg = tid >> 7;
      unsigned short buf[32];
#pragma unroll
      for (int i2=0;i2<32;i2++) buf[i2] = L[(sg*32 + i2)*LTS + hd*128 + dh];
      unsigned short* dst = Vt + ((size_t)bh*DHq + dh)*Sq + sb + sg*32;
#pragma unroll
      for (int i2=0;i2<4;i2++)
        *(s16x8*)&dst[i2*8] = *(const s16x8*)&buf[i2*8];
    }
  }
}

// ---------------- GEMM2: 8-phase 128x256, f32 out; RMS scale from ssqp ------
__global__ __launch_bounds__(512, 1) void k_gemm2_8ph(const unsigned short* __restrict__ A,
                                                      const unsigned short* __restrict__ Bt,
                                                      const float* __restrict__ bias,
                                                      const float* __restrict__ ssqp,
                                                      float* __restrict__ C){
  const int K = 2048, N = 2048, NI = 16;
  const int bid = blockIdx.x;
  const int xcd = bid & 7, u = bid >> 3;
  const int m0 = (xcd*4 + (u & 3)) * 128;
  const int n0 = (u >> 2) * 256;

  const int tid = threadIdx.x;
  const int lane = tid & 63, w = tid >> 6, g = lane >> 4, c = lane & 15;
  const int wm = w >> 2, wn = w & 3;

  __shared__ __align__(16) unsigned short L[49152];   // 96 KB

  const int srow = tid >> 2, spc = tid & 3;
  const int ssw = (spc ^ ((srow >> 1) & 3)) << 3;
  const unsigned short* aSrc  = A  + (size_t)(m0 + srow      )*K + ssw;
  const unsigned short* bSrc0 = Bt + (size_t)(n0 + srow      )*K + ssw;
  const unsigned short* bSrc1 = Bt + (size_t)(n0 + srow + 128)*K + ssw;

  auto stA = [&](int t, int h){
    gload_lds16(aSrc + t*64 + h*32, &L[((t&1)*2 + h)*4096 + tid*8]);
  };
  auto stB = [&](int t, int h, int uu){
    const unsigned short* s = (uu==0) ? bSrc0 : bSrc1;
    gload_lds16(s + t*64 + h*32, &L[16384 + ((t&1)*2 + h)*8192 + uu*4096 + tid*8]);
  };

  int aoff[4], boff[4];
#pragma unroll
  for (int mf=0; mf<4; ++mf){
    int row = wm*64 + mf*16 + c;
    aoff[mf] = row*32 + ((g ^ ((row>>1)&3)) << 3);
  }
#pragma unroll
  for (int nf=0; nf<4; ++nf){
    int row = wn*64 + nf*16 + c;
    boff[nf] = row*32 + ((g ^ ((row>>1)&3)) << 3);
  }

  f32x4 acc[4][4];
#pragma unroll
  for (int i=0;i<4;i++)
#pragma unroll
    for (int j=0;j<4;j++)
#pragma unroll
      for (int r=0;r<4;r++) acc[i][j][r] = 0.f;

  auto RDA = [&](int b, int h, s16x8* af){
    const int ab = (b*2 + h)*4096;
#pragma unroll
    for (int mf=0; mf<4; ++mf) af[mf] = *(const s16x8*)&L[ab + aoff[mf]];
  };
  auto RDB = [&](int b, int h, int nh, s16x8* bf){
    const int bb = 16384 + (b*2 + h)*8192;
#pragma unroll
    for (int j=0; j<2; ++j) bf[j] = *(const s16x8*)&L[bb + boff[nh*2 + j]];
  };
  auto MM = [&](s16x8* af, s16x8* bf, int nh){
    __builtin_amdgcn_s_setprio(1);
#pragma unroll
    for (int mf=0; mf<4; ++mf)
#pragma unroll
      for (int j=0; j<2; ++j)
        acc[mf][nh*2+j] = __builtin_amdgcn_mfma_f32_16x16x32_bf16(af[mf], bf[j], acc[mf][nh*2+j], 0,0,0);
    __builtin_amdgcn_s_setprio(0);
  };
  auto BAR = [&](){
    __builtin_amdgcn_sched_barrier(0);
    __builtin_amdgcn_s_barrier();
    __builtin_amdgcn_sched_barrier(0);
  };

  stA(0,0); stB(0,0,0); stB(0,0,1);
  stA(0,1); stB(0,1,0); stB(0,1,1);
  stA(1,0); stB(1,0,0); stB(1,0,1);
  asm volatile("s_waitcnt vmcnt(3)" ::: "memory");
  __builtin_amdgcn_s_barrier();

  for (int i=0; i<NI; ++i){
    const int T0 = 2*i, T1 = 2*i + 1;
    const bool st = (i < NI-1);
    s16x8 af[4], bf[2];
    RDA(0,0,af); RDB(0,0,0,bf);
    stA(T1,1); stB(T1,1,0);
    BAR(); MM(af,bf,0); BAR();
    RDB(0,0,1,bf);
    stB(T1,1,1);
    BAR(); MM(af,bf,1); BAR();
    RDA(0,1,af); RDB(0,1,0,bf);
    if (st){ stA(T0+2,0); stB(T0+2,0,0); }
    BAR(); MM(af,bf,0); BAR();
    RDB(0,1,1,bf);
    if (st){ stB(T0+2,0,1); }
    __builtin_amdgcn_sched_barrier(0);
    if (st) asm volatile("s_waitcnt vmcnt(3)" ::: "memory");
    else    asm volatile("s_waitcnt vmcnt(0)" ::: "memory");
    BAR(); MM(af,bf,1); BAR();
    RDA(1,0,af); RDB(1,0,0,bf);
    if (st){ stA(T0+2,1); stB(T0+2,1,0); }
    BAR(); MM(af,bf,0); BAR();
    RDB(1,0,1,bf);
    if (st){ stB(T0+2,1,1); }
    BAR(); MM(af,bf,1); BAR();
    RDA(1,1,af); RDB(1,1,0,bf);
    if (st){ stA(T1+2,0); stB(T1+2,0,0); }
    BAR(); MM(af,bf,0); BAR();
    RDB(1,1,1,bf);
    if (st){ stB(T1+2,0,1); }
    __builtin_amdgcn_sched_barrier(0);
    if (st) asm volatile("s_waitcnt vmcnt(3)" ::: "memory");
    else    asm volatile("s_waitcnt vmcnt(0)" ::: "memory");
    BAR(); MM(af,bf,1); BAR();
  }

  // ---- per-row RMS scale from head partials ----
  __syncthreads();                         // L free after main loop
  float* SS = (float*)&L[0];               // [128] rsqrt scales
  if (tid < 128){
    const float* p = ssqp + (size_t)(m0 + tid)*16;
    float s = 0.f;
#pragma unroll
    for (int h=0; h<16; ++h) s += p[h];
    SS[tid] = rsqrtf(s*(1.f/2048.f) + 1e-6f);
  }
  __syncthreads();

#pragma unroll
  for (int nf=0; nf<4; ++nf){
    const int col = n0 + wn*64 + nf*16 + c;
    const float bv = bias[col];
#pragma unroll
    for (int mf=0; mf<4; ++mf){
      const int rowl = wm*64 + mf*16 + g*4;
#pragma unroll
      for (int r=0; r<4; ++r)
        C[(size_t)(m0+rowl+r)*N + col] = acc[mf][nf][r]*SS[rowl+r] + bv;
    }
  }
}

// ---------------- causal MFMA flash attention (swapped-operand) -------------
__global__ __launch_bounds__(256, 2) void k_attn(const unsigned short* __restrict__ Qp,
                                                 const unsigned short* __restrict__ Kp,
                                                 const unsigned short* __restrict__ Vt,
                                                 unsigned short* __restrict__ Ar,
                                                 float* __restrict__ ssqp){
  const int L = blockIdx.x;
  const int xcdL = L & 7, j = L >> 3;
  const int bh = xcdL*4 + ((j & 31) >> 3);
  const int qtile = (j < 32) ? (8 + (j & 7)) : (7 - (j & 7));
  const int b = bh >> 4, h = bh & 15;
  const int tid = threadIdx.x;
  const int w = tid >> 6, lane = tid & 63, g = lane >> 4, c = lane & 15;
  const int r0w = qtile*128 + w*32;

  const unsigned short* Qh = Qp + (size_t)bh * Sq * DHq;
  const unsigned short* Kh = Kp + (size_t)bh * Sq * DHq;
  const unsigned short* Vh = Vt + (size_t)bh * DHq * Sq;

  __shared__ __align__(16) unsigned short Ks[2][64*128];   // 32 KB
  __shared__ __align__(16) unsigned short Vs[2][128*64];   // 32 KB
  __shared__ __align__(16) unsigned short Pl[4][32*64];    // 16 KB  (per-wave [q][k])
  unsigned short* Pw = &Pl[w][0];

  s16x8 qf[2][4];
#pragma unroll
  for (int mi=0;mi<2;mi++)
#pragma unroll
    for (int kc=0;kc<4;kc++)
      qf[mi][kc] = *(const s16x8*)&Qh[(size_t)(r0w + mi*16 + c)*DHq + kc*32 + g*8];

  f32x4 acc[2][8];
#pragma unroll
  for (int mi=0;mi<2;mi++)
#pragma unroll
    for (int dt=0;dt<8;dt++)
#pragma unroll
      for (int r=0;r<4;r++) acc[mi][dt][r] = 0.f;
  float m_r[2] = { -INFINITY, -INFINITY };
  float l_p[2] = { 0.f, 0.f };             // per-lane PARTIAL sums

  const int nsteps = 2*qtile + 2;

  auto stage = [&](int j0s, int bufi){
#pragma unroll
    for (int i=0;i<4;i++){
      int pk = tid + i*256;              // K: 1024 chunks of 16B
      int row = pk>>4, pcc = pk&15;
      gload_lds16(&Kh[(size_t)(j0s+row)*DHq + ((pcc^(row&7))<<3)], &Ks[bufi][pk*8]);
    }
#pragma unroll
    for (int i=0;i<4;i++){
      int pk = tid + i*256;              // V: 1024 chunks of 16B
      int row = pk>>3, pcc = pk&7;
      gload_lds16(&Vh[(size_t)row*Sq + j0s + ((pcc^(row&7))<<3)], &Vs[bufi][pk*8]);
    }
  };

  stage(0, 0);
  __syncthreads();

  for (int t=0; t<nsteps; ++t){
    const int j0 = t*64;
    if (t+1 < nsteps) stage((t+1)*64, (t+1)&1);

    if (j0 <= r0w + 31){
      const unsigned short* Kc = &Ks[t&1][0];
      const unsigned short* Vc = &Vs[t&1][0];

      // ---- S^T = K.Q^T ----
      f32x4 sv[2][4];
#pragma unroll
      for (int mi=0;mi<2;mi++)
#pragma unroll
        for (int js=0;js<4;js++)
#pragma unroll
          for (int r=0;r<4;r++) sv[mi][js][r] = 0.f;

      __builtin_amdgcn_s_setprio(1);
#pragma unroll
      for (int js=0;js<4;js++){
        s16x8 kf[4];
#pragma unroll
        for (int kc=0;kc<4;kc++)
          kf[kc] = *(const s16x8*)&Kc[(js*16 + c)*128 + (((kc*4+g)^(c&7))<<3)];
#pragma unroll
        for (int mi=0;mi<2;mi++)
#pragma unroll
          for (int kc=0;kc<4;kc++)
            sv[mi][js] = __builtin_amdgcn_mfma_f32_16x16x32_bf16(kf[kc], qf[mi][kc], sv[mi][js], 0,0,0);
      }
      __builtin_amdgcn_s_setprio(0);

      if (j0 + 63 > r0w){
#pragma unroll
        for (int mi=0;mi<2;mi++){
          const int q = r0w + mi*16 + c;
#pragma unroll
          for (int js=0;js<4;js++)
#pragma unroll
            for (int r=0;r<4;r++)
              if (j0 + js*16 + g*4 + r > q) sv[mi][js][r] = -INFINITY;
        }
      }

      float pmx[2];
#pragma unroll
      for (int mi=0;mi<2;mi++){
        float mx = fmaxf(fmaxf(sv[mi][0][0],sv[mi][0][1]), fmaxf(sv[mi][0][2],sv[mi][0][3]));
#pragma unroll
        for (int js=1;js<4;js++){
          float a = fmaxf(fmaxf(sv[mi][js][0],sv[mi][js][1]), fmaxf(sv[mi][js][2],sv[mi][js][3]));
          mx = fmaxf(mx, a);
        }
        mx = fmaxf(mx, __shfl_xor(mx, 16));
        mx = fmaxf(mx, __shfl_xor(mx, 32));
        pmx[mi] = mx;
      }
      int need = (pmx[0] > m_r[0] + 8.f) | (pmx[1] > m_r[1] + 8.f);
      if (__any(need)){
#pragma unroll
        for (int mi=0;mi<2;mi++){
          float mnew = fmaxf(m_r[mi], pmx[mi]);
          float corr = exp2f(m_r[mi] - mnew);
          l_p[mi] *= corr;
          m_r[mi] = mnew;
#pragma unroll
          for (int dt=0;dt<8;dt++)
#pragma unroll
            for (int r=0;r<4;r++) acc[mi][dt][r] *= corr;
        }
      }
#pragma unroll
      for (int mi=0;mi<2;mi++){
        const float mm = m_r[mi];
        const int rowoff = (mi*16 + c)*64;
#pragma unroll
        for (int js=0;js<4;js++){
          float e0 = exp2f(sv[mi][js][0] - mm);
          float e1 = exp2f(sv[mi][js][1] - mm);
          float e2 = exp2f(sv[mi][js][2] - mm);
          float e3 = exp2f(sv[mi][js][3] - mm);
          l_p[mi] += (e0+e1)+(e2+e3);
          uint2 pk2;
          pk2.x = cvtpk_bf16(e0, e1);
          pk2.y = cvtpk_bf16(e2, e3);
          const int kc8 = js*2 + (g>>1);
          *(uint2*)&Pw[rowoff + ((kc8 ^ (c&7))<<3) + (g&1)*4] = pk2;
        }
      }

      s16x8 pfr[2][2];
#pragma unroll
      for (int mi=0;mi<2;mi++)
#pragma unroll
        for (int kc=0;kc<2;kc++)
          pfr[mi][kc] = *(const s16x8*)&Pw[(mi*16 + c)*64 + (((kc*4+g)^(c&7))<<3)];
      __builtin_amdgcn_s_setprio(1);
#pragma unroll
      for (int dt=0; dt<8; dt++){
#pragma unroll
        for (int kc=0;kc<2;kc++){
          s16x8 vfr = *(const s16x8*)&Vc[(dt*16 + c)*64 + (((kc*4+g)^(c&7))<<3)];
#pragma unroll
          for (int mi=0;mi<2;mi++)
            acc[mi][dt] = __builtin_amdgcn_mfma_f32_16x16x32_bf16(vfr, pfr[mi][kc], acc[mi][dt], 0,0,0);
        }
      }
      __builtin_amdgcn_s_setprio(0);
    }
    __syncthreads();
  }

  // ---- epilogue: normalize, write O^T + per-head sumsq partial ----
#pragma unroll
  for (int mi=0;mi<2;mi++){
    float l = l_p[mi];
    l += __shfl_xor(l, 16);
    l += __shfl_xor(l, 32);
    const float inv = 1.f / l;
    const int row = r0w + mi*16 + c;
    unsigned short* dst = &Ar[((size_t)(b*Sq + row))*Dq + h*DHq];
    float sq = 0.f;
#pragma unroll
    for (int dt=0; dt<8; dt++){
      float v0 = acc[mi][dt][0]*inv, v1 = acc[mi][dt][1]*inv;
      float v2 = acc[mi][dt][2]*inv, v3 = acc[mi][dt][3]*inv;
      sq += v0*v0 + v1*v1 + v2*v2 + v3*v3;
      uint2 o2;
      o2.x = cvtpk_bf16(v0, v1);
      o2.y = cvtpk_bf16(v2, v3);
      *(uint2*)&dst[dt*16 + g*4] = o2;
    }
    sq += __shfl_xor(sq, 16);
    sq += __shfl_xor(sq, 32);
    if (g == 0)
      ssqp[(size_t)(b*Sq + row)*16 + h] = sq;
  }
}

extern "C" void kernel_launch(void* const* d_in, const int* in_sizes, int n_in,
                              void* d_out, int out_size, void* d_ws, size_t ws_size,
                              hipStream_t stream){
  const float* x     = (const float*)d_in[0];
  const float* rp    = (const float*)d_in[1];
  const float* Win   = (const float*)d_in[2];
  const float* b_in  = (const float*)d_in[3];
  const float* Wout  = (const float*)d_in[4];
  const float* b_out = (const float*)d_in[5];
  const float* qk_w  = (const float*)d_in[6];
  const float* out_w = (const float*)d_in[7];
  float* outp = (float*)d_out;

  if (ws_size < (160ull<<20)) return;   // need 160 MiB scratch

  char* ws = (char*)d_ws;
  unsigned short* Xb    = (unsigned short*)(ws);                 // 16 MiB
  unsigned short* Wb    = (unsigned short*)(ws + (16ull<<20));   // 24 MiB
  unsigned short* Woutb = (unsigned short*)(ws + (40ull<<20));   //  8 MiB
  float*          ssqp  = (float*)         (ws + (48ull<<20));   // 256 KiB
  float2*         rpcs  = (float2*)        (ws + (49ull<<20));   //  1 MiB
  unsigned short* Qp    = (unsigned short*)(ws + (96ull<<20));   // 16 MiB
  unsigned short* Kp    = (unsigned short*)(ws + (112ull<<20));  // 16 MiB
  unsigned short* Vt    = (unsigned short*)(ws + (128ull<<20));  // 16 MiB
  unsigned short* Ar    = (unsigned short*)(ws + (144ull<<20));  // 16 MiB

  // 1) fused converts (out_w folded into Woutb) + RoPE cos/sin table
  k_convert3<<<2048, 256, 0, stream>>>(x, Win, Wout, out_w, rp, Xb, Wb, Woutb, rpcs);
  // 2) QKV GEMM (128x384 8-phase) + fused RoPE/RMS-norm/V-transpose epilogue
  k_gemm1f<<<512, 512, 0, stream>>>(Xb, Wb, b_in, rpcs, qk_w, Qp, Kp, Vt);
  // 3) causal flash attention (XCD-local) + per-head sumsq partials
  k_attn<<<512, 256, 0, stream>>>(Qp, Kp, Vt, Ar, ssqp);
  // 4) Out = rms_scale(Ar) * (Ar . (out_w*Wout)^T) + b_out
  k_gemm2_8ph<<<256, 512, 0, stream>>>(Ar, Woutb, b_out, ssqp, outp);
}

// Round 20
// 261.579 us; speedup vs baseline: 1.0449x; 1.0449x over previous
//
#include <hip/hip_runtime.h>
#include <cstdint>
#include <cstddef>

// Problem constants (B,S,D,H) = (2,2048,2048,16), DH=128
#define Bq  2
#define Sq  2048
#define Dq  2048
#define Hq  16
#define DHq 128
#define E3q 6144   // 3*D

typedef __attribute__((ext_vector_type(8))) short s16x8;   // 8 bf16 (4 VGPRs)
typedef __attribute__((ext_vector_type(4))) float f32x4;   // MFMA accumulator

__device__ __forceinline__ unsigned short f2bf(float f){
  union { float f; unsigned u; } v; v.f = f;
  unsigned r = v.u + 0x7FFFu + ((v.u >> 16) & 1u);   // round-to-nearest-even
  return (unsigned short)(r >> 16);
}
__device__ __forceinline__ float bf2f(unsigned short b){
  union { unsigned u; float f; } v; v.u = ((unsigned)b) << 16;
  return v.f;
}
// pack two f32 -> two bf16 in one op (no builtin on gfx950; T12 recipe)
__device__ __forceinline__ unsigned cvtpk_bf16(float lo, float hi){
  unsigned r;
  asm("v_cvt_pk_bf16_f32 %0, %1, %2" : "=v"(r) : "v"(lo), "v"(hi));
  return r;
}

// async global->LDS, 16B per lane. LDS dest must be wave-uniform base + lane*16.
__device__ __forceinline__ void gload_lds16(const void* g, void* l){
  __builtin_amdgcn_global_load_lds(
      (const __attribute__((address_space(1))) void*)g,
      (__attribute__((address_space(3))) void*)l, 16, 0, 0);
}

// ------ fused fp32->bf16 converts + RoPE (cos,sin) table ------
__global__ __launch_bounds__(256) void k_convert3(const float* __restrict__ x,
                                                  const float* __restrict__ win,
                                                  const float* __restrict__ wout,
                                                  const float* __restrict__ out_w,
                                                  const float* __restrict__ rp,
                                                  unsigned short* __restrict__ xb,
                                                  unsigned short* __restrict__ wb,
                                                  unsigned short* __restrict__ woutb,
                                                  float2* __restrict__ rpcs){
  const int NX = (Bq*Sq*Dq)/4;
  const int NW = (E3q*Dq)/4;
  const int NO = (Dq*Dq)/4;
  const int NR = (Sq*64)/4;
  const int total = NX + NW + NO + NR;
  int stride = gridDim.x * blockDim.x;
  for (int i = blockIdx.x*blockDim.x + threadIdx.x; i < total; i += stride){
    if (i < NX + NW){
      const float* src; unsigned short* dst; int j;
      if (i < NX){ src = x; dst = xb; j = i; }
      else { src = win; dst = wb; j = i - NX; }
      float4 v = reinterpret_cast<const float4*>(src)[j];
      ushort4 o;
      o.x = f2bf(v.x); o.y = f2bf(v.y); o.z = f2bf(v.z); o.w = f2bf(v.w);
      reinterpret_cast<ushort4*>(dst)[j] = o;
    } else if (i < NX + NW + NO){
      int j = i - NX - NW;
      float4 v = reinterpret_cast<const float4*>(wout)[j];
      float4 w = reinterpret_cast<const float4*>(out_w)[j & 511];
      ushort4 o;
      o.x = f2bf(v.x*w.x); o.y = f2bf(v.y*w.y); o.z = f2bf(v.z*w.z); o.w = f2bf(v.w*w.w);
      reinterpret_cast<ushort4*>(woutb)[j] = o;
    } else {
      int j = i - NX - NW - NO;
      float4 a = reinterpret_cast<const float4*>(rp)[j];
      float sn0,cs0,sn1,cs1,sn2,cs2,sn3,cs3;
      sincosf(a.x,&sn0,&cs0); sincosf(a.y,&sn1,&cs1);
      sincosf(a.z,&sn2,&cs2); sincosf(a.w,&sn3,&cs3);
      float4 p0 = make_float4(cs0,sn0,cs1,sn1);
      float4 p1 = make_float4(cs2,sn2,cs3,sn3);
      reinterpret_cast<float4*>(rpcs)[j*2  ] = p0;
      reinterpret_cast<float4*>(rpcs)[j*2+1] = p1;
    }
  }
}

// ---------------- GEMM1 fused: 8-phase 128x256 + RoPE/RMS/transpose epilogue
__global__ __launch_bounds__(512, 1) void k_gemm1f(const unsigned short* __restrict__ A,
                                                   const unsigned short* __restrict__ Bt,
                                                   const float* __restrict__ bias,
                                                   const float2* __restrict__ rpcs,
                                                   const float* __restrict__ qk_w,
                                                   unsigned short* __restrict__ Qp,
                                                   unsigned short* __restrict__ Kp,
                                                   unsigned short* __restrict__ Vt){
  const int K = 2048, NI = 16;
  const int bid = blockIdx.x;
  const int xcd = bid & 7, u = bid >> 3;          // 96 per XCD
  const int m0 = (xcd*4 + (u & 3)) * 128;         // 32 M-tiles, 4 per XCD
  const int n0 = (u >> 2) * 256;                  // 24 N-tiles, col-major in chunk

  const int tid = threadIdx.x;
  const int lane = tid & 63, w = tid >> 6, g = lane >> 4, c = lane & 15;
  const int wm = w >> 2, wn = w & 3;              // 2 x 4 waves

  __shared__ __align__(16) unsigned short L[49152];   // 96 KB

  const int srow = tid >> 2, spc = tid & 3;
  const int ssw = (spc ^ ((srow >> 1) & 3)) << 3;
  const unsigned short* aSrc  = A  + (size_t)(m0 + srow      )*K + ssw;
  const unsigned short* bSrc0 = Bt + (size_t)(n0 + srow      )*K + ssw;
  const unsigned short* bSrc1 = Bt + (size_t)(n0 + srow + 128)*K + ssw;

  auto stA = [&](int t, int h){
    gload_lds16(aSrc + t*64 + h*32, &L[((t&1)*2 + h)*4096 + tid*8]);
  };
  auto stB = [&](int t, int h, int uu){
    const unsigned short* s = (uu==0) ? bSrc0 : bSrc1;
    gload_lds16(s + t*64 + h*32, &L[16384 + ((t&1)*2 + h)*8192 + uu*4096 + tid*8]);
  };

  int aoff[4], boff[4];
#pragma unroll
  for (int mf=0; mf<4; ++mf){
    int row = wm*64 + mf*16 + c;
    aoff[mf] = row*32 + ((g ^ ((row>>1)&3)) << 3);
  }
#pragma unroll
  for (int nf=0; nf<4; ++nf){
    int row = wn*64 + nf*16 + c;
    boff[nf] = row*32 + ((g ^ ((row>>1)&3)) << 3);
  }

  f32x4 acc[4][4];
#pragma unroll
  for (int i=0;i<4;i++)
#pragma unroll
    for (int j=0;j<4;j++)
#pragma unroll
      for (int r=0;r<4;r++) acc[i][j][r] = 0.f;

  auto RDA = [&](int b, int h, s16x8* af){
    const int ab = (b*2 + h)*4096;
#pragma unroll
    for (int mf=0; mf<4; ++mf) af[mf] = *(const s16x8*)&L[ab + aoff[mf]];
  };
  auto RDB = [&](int b, int h, int nh, s16x8* bf){
    const int bb = 16384 + (b*2 + h)*8192;
#pragma unroll
    for (int j=0; j<2; ++j) bf[j] = *(const s16x8*)&L[bb + boff[nh*2 + j]];
  };
  auto MM = [&](s16x8* af, s16x8* bf, int nh){
    __builtin_amdgcn_s_setprio(1);
#pragma unroll
    for (int mf=0; mf<4; ++mf)
#pragma unroll
      for (int j=0; j<2; ++j)
        acc[mf][nh*2+j] = __builtin_amdgcn_mfma_f32_16x16x32_bf16(af[mf], bf[j], acc[mf][nh*2+j], 0,0,0);
    __builtin_amdgcn_s_setprio(0);
  };
  auto BAR = [&](){
    __builtin_amdgcn_sched_barrier(0);
    __builtin_amdgcn_s_barrier();
    __builtin_amdgcn_sched_barrier(0);
  };

  stA(0,0); stB(0,0,0); stB(0,0,1);
  stA(0,1); stB(0,1,0); stB(0,1,1);
  stA(1,0); stB(1,0,0); stB(1,0,1);
  asm volatile("s_waitcnt vmcnt(3)" ::: "memory");
  __builtin_amdgcn_s_barrier();

  for (int i=0; i<NI; ++i){
    const int T0 = 2*i, T1 = 2*i + 1;
    const bool st = (i < NI-1);
    s16x8 af[4], bf[2];
    RDA(0,0,af); RDB(0,0,0,bf);
    stA(T1,1); stB(T1,1,0);
    BAR(); MM(af,bf,0); BAR();
    RDB(0,0,1,bf);
    stB(T1,1,1);
    BAR(); MM(af,bf,1); BAR();
    RDA(0,1,af); RDB(0,1,0,bf);
    if (st){ stA(T0+2,0); stB(T0+2,0,0); }
    BAR(); MM(af,bf,0); BAR();
    RDB(0,1,1,bf);
    if (st){ stB(T0+2,0,1); }
    __builtin_amdgcn_sched_barrier(0);
    if (st) asm volatile("s_waitcnt vmcnt(3)" ::: "memory");
    else    asm volatile("s_waitcnt vmcnt(0)" ::: "memory");
    BAR(); MM(af,bf,1); BAR();
    RDA(1,0,af); RDB(1,0,0,bf);
    if (st){ stA(T0+2,1); stB(T0+2,1,0); }
    BAR(); MM(af,bf,0); BAR();
    RDB(1,0,1,bf);
    if (st){ stB(T0+2,1,1); }
    BAR(); MM(af,bf,1); BAR();
    RDA(1,1,af); RDB(1,1,0,bf);
    if (st){ stA(T1+2,0); stB(T1+2,0,0); }
    BAR(); MM(af,bf,0); BAR();
    RDB(1,1,1,bf);
    if (st){ stB(T1+2,0,1); }
    __builtin_amdgcn_sched_barrier(0);
    if (st) asm volatile("s_waitcnt vmcnt(3)" ::: "memory");
    else    asm volatile("s_waitcnt vmcnt(0)" ::: "memory");
    BAR(); MM(af,bf,1); BAR();
  }

  // ================= fused epilogue =================
  const int btype = (n0 < 2048) ? 0 : (n0 < 4096) ? 1 : 2;   // Q, K, V
  const int b  = m0 >> 11;                 // batch
  const int sb = m0 & 2047;                // token base
  const int h0 = (n0 & 2047) >> 7;         // base head of this 256-col tile
  const int LTS = 264;                     // padded bf16 row stride
  const float QSCALE = 0.08838834764831845f * 1.4426950408889634f;

#pragma unroll
  for (int nf=0; nf<4; ++nf){
    const float bv = bias[n0 + wn*64 + nf*16 + c];
#pragma unroll
    for (int mf=0; mf<4; ++mf)
#pragma unroll
      for (int r=0; r<4; ++r) acc[mf][nf][r] += bv;
  }

  __syncthreads();   // main-loop LDS use finished; L free

  if (btype < 2){
    float s2[4][4];
#pragma unroll
    for (int mf=0;mf<4;mf++)
#pragma unroll
      for (int r=0;r<4;r++){
        float s = 0.f;
#pragma unroll
        for (int nf=0;nf<4;nf++){ float v = acc[mf][nf][r]; s += v*v; }
        s2[mf][r] = s;
      }
#pragma unroll
    for (int m=1;m<16;m<<=1)
#pragma unroll
      for (int mf=0;mf<4;mf++)
#pragma unroll
        for (int r=0;r<4;r++) s2[mf][r] += __shfl_xor(s2[mf][r], m);
    float* Ssum = (float*)&L[0];
    if (c==0 && (wn&1)==0){
#pragma unroll
      for (int mf=0;mf<4;mf++)
#pragma unroll
        for (int r=0;r<4;r++)
          Ssum[(wm*64+mf*16+g*4+r)*2 + (wn>>1)] = s2[mf][r];
    }
    __syncthreads();
    if (c==0 && (wn&1)==1){
#pragma unroll
      for (int mf=0;mf<4;mf++)
#pragma unroll
        for (int r=0;r<4;r++)
          Ssum[(wm*64+mf*16+g*4+r)*2 + (wn>>1)] += s2[mf][r];
    }
    __syncthreads();
    float rsc[4][4];
#pragma unroll
    for (int mf=0;mf<4;mf++)
#pragma unroll
      for (int r=0;r<4;r++)
        rsc[mf][r] = rsqrtf(Ssum[(wm*64+mf*16+g*4+r)*2 + (wn>>1)]*(1.f/128.f) + 1e-6f);
    __syncthreads();

    const float qmul = (btype==0) ? QSCALE : 1.f;
    float wq[4];
    int pp[4];
#pragma unroll
    for (int nf=0;nf<4;nf++){
      wq[nf] = qk_w[(wn*64+nf*16+c)&127];
      pp[nf] = ((wn*64+nf*16+c)&127) >> 1;
    }

#pragma unroll
    for (int mf=0;mf<4;mf++)
#pragma unroll
      for (int r=0;r<4;r++){
        const int rowl = wm*64+mf*16+g*4+r;
        const int s = sb + rowl;
        const float sc = rsc[mf][r] * qmul;
#pragma unroll
        for (int nf=0;nf<4;nf++){
          float2 t = rpcs[s*64 + pp[nf]];
          float v  = acc[mf][nf][r];
          float pv = __shfl_xor(v, 1);
          float rot = ((c&1)==0) ? (v*t.x - pv*t.y) : (pv*t.y + v*t.x);
          L[rowl*LTS + wn*64+nf*16+c] = f2bf(rot * sc * wq[nf]);
        }
      }
    __syncthreads();
    {
      const int rw = tid >> 2, hd = (tid>>1)&1, hf = tid&1;
      const int bh = b*Hq + h0 + hd;
      unsigned short* dst = ((btype==0) ? Qp : Kp)
                          + ((size_t)bh*Sq + sb + rw)*DHq + hf*64;
      const unsigned short* srcl = &L[rw*LTS + hd*128 + hf*64];
#pragma unroll
      for (int i2=0;i2<8;i2++)
        *(s16x8*)&dst[i2*8] = *(const s16x8*)&srcl[i2*8];
    }
  } else {
#pragma unroll
    for (int mf=0;mf<4;mf++)
#pragma unroll
      for (int r=0;r<4;r++){
        const int rowl = wm*64+mf*16+g*4+r;
#pragma unroll
        for (int nf=0;nf<4;nf++)
          L[rowl*LTS + wn*64+nf*16+c] = f2bf(acc[mf][nf][r]);
      }
    __syncthreads();
    {
      const int dh2 = tid >> 1, hfr = (tid & 1) * 64;
      const int hd = dh2 >> 7, dh = dh2 & 127;
      const int bh = b*Hq + h0 + hd;
      unsigned short buf[64];
#pragma unroll
      for (int i2=0;i2<64;i2++) buf[i2] = L[(hfr+i2)*LTS + dh2];
      unsigned short* dst = Vt + ((size_t)bh*DHq + dh)*Sq + sb + hfr;
#pragma unroll
      for (int i2=0;i2<8;i2++)
        *(s16x8*)&dst[i2*8] = *(const s16x8*)&buf[i2*8];
    }
  }
}

// ---------------- GEMM2: 8-phase 128x256, f32 out; RMS scale from ssqp ------
// ssqp[row][h] = per-head partial sumsq of Ar row (written by k_attn).
__global__ __launch_bounds__(512, 1) void k_gemm2_8ph(const unsigned short* __restrict__ A,
                                                      const unsigned short* __restrict__ Bt,
                                                      const float* __restrict__ bias,
                                                      const float* __restrict__ ssqp,
                                                      float* __restrict__ C){
  const int K = 2048, N = 2048, NI = 16;
  const int bid = blockIdx.x;
  const int xcd = bid & 7, u = bid >> 3;
  const int m0 = (xcd*4 + (u & 3)) * 128;
  const int n0 = (u >> 2) * 256;

  const int tid = threadIdx.x;
  const int lane = tid & 63, w = tid >> 6, g = lane >> 4, c = lane & 15;
  const int wm = w >> 2, wn = w & 3;

  __shared__ __align__(16) unsigned short L[49152];   // 96 KB

  const int srow = tid >> 2, spc = tid & 3;
  const int ssw = (spc ^ ((srow >> 1) & 3)) << 3;
  const unsigned short* aSrc  = A  + (size_t)(m0 + srow      )*K + ssw;
  const unsigned short* bSrc0 = Bt + (size_t)(n0 + srow      )*K + ssw;
  const unsigned short* bSrc1 = Bt + (size_t)(n0 + srow + 128)*K + ssw;

  auto stA = [&](int t, int h){
    gload_lds16(aSrc + t*64 + h*32, &L[((t&1)*2 + h)*4096 + tid*8]);
  };
  auto stB = [&](int t, int h, int uu){
    const unsigned short* s = (uu==0) ? bSrc0 : bSrc1;
    gload_lds16(s + t*64 + h*32, &L[16384 + ((t&1)*2 + h)*8192 + uu*4096 + tid*8]);
  };

  int aoff[4], boff[4];
#pragma unroll
  for (int mf=0; mf<4; ++mf){
    int row = wm*64 + mf*16 + c;
    aoff[mf] = row*32 + ((g ^ ((row>>1)&3)) << 3);
  }
#pragma unroll
  for (int nf=0; nf<4; ++nf){
    int row = wn*64 + nf*16 + c;
    boff[nf] = row*32 + ((g ^ ((row>>1)&3)) << 3);
  }

  f32x4 acc[4][4];
#pragma unroll
  for (int i=0;i<4;i++)
#pragma unroll
    for (int j=0;j<4;j++)
#pragma unroll
      for (int r=0;r<4;r++) acc[i][j][r] = 0.f;

  auto RDA = [&](int b, int h, s16x8* af){
    const int ab = (b*2 + h)*4096;
#pragma unroll
    for (int mf=0; mf<4; ++mf) af[mf] = *(const s16x8*)&L[ab + aoff[mf]];
  };
  auto RDB = [&](int b, int h, int nh, s16x8* bf){
    const int bb = 16384 + (b*2 + h)*8192;
#pragma unroll
    for (int j=0; j<2; ++j) bf[j] = *(const s16x8*)&L[bb + boff[nh*2 + j]];
  };
  auto MM = [&](s16x8* af, s16x8* bf, int nh){
    __builtin_amdgcn_s_setprio(1);
#pragma unroll
    for (int mf=0; mf<4; ++mf)
#pragma unroll
      for (int j=0; j<2; ++j)
        acc[mf][nh*2+j] = __builtin_amdgcn_mfma_f32_16x16x32_bf16(af[mf], bf[j], acc[mf][nh*2+j], 0,0,0);
    __builtin_amdgcn_s_setprio(0);
  };
  auto BAR = [&](){
    __builtin_amdgcn_sched_barrier(0);
    __builtin_amdgcn_s_barrier();
    __builtin_amdgcn_sched_barrier(0);
  };

  stA(0,0); stB(0,0,0); stB(0,0,1);
  stA(0,1); stB(0,1,0); stB(0,1,1);
  stA(1,0); stB(1,0,0); stB(1,0,1);
  asm volatile("s_waitcnt vmcnt(3)" ::: "memory");
  __builtin_amdgcn_s_barrier();

  for (int i=0; i<NI; ++i){
    const int T0 = 2*i, T1 = 2*i + 1;
    const bool st = (i < NI-1);
    s16x8 af[4], bf[2];
    RDA(0,0,af); RDB(0,0,0,bf);
    stA(T1,1); stB(T1,1,0);
    BAR(); MM(af,bf,0); BAR();
    RDB(0,0,1,bf);
    stB(T1,1,1);
    BAR(); MM(af,bf,1); BAR();
    RDA(0,1,af); RDB(0,1,0,bf);
    if (st){ stA(T0+2,0); stB(T0+2,0,0); }
    BAR(); MM(af,bf,0); BAR();
    RDB(0,1,1,bf);
    if (st){ stB(T0+2,0,1); }
    __builtin_amdgcn_sched_barrier(0);
    if (st) asm volatile("s_waitcnt vmcnt(3)" ::: "memory");
    else    asm volatile("s_waitcnt vmcnt(0)" ::: "memory");
    BAR(); MM(af,bf,1); BAR();
    RDA(1,0,af); RDB(1,0,0,bf);
    if (st){ stA(T0+2,1); stB(T0+2,1,0); }
    BAR(); MM(af,bf,0); BAR();
    RDB(1,0,1,bf);
    if (st){ stB(T0+2,1,1); }
    BAR(); MM(af,bf,1); BAR();
    RDA(1,1,af); RDB(1,1,0,bf);
    if (st){ stA(T1+2,0); stB(T1+2,0,0); }
    BAR(); MM(af,bf,0); BAR();
    RDB(1,1,1,bf);
    if (st){ stB(T1+2,0,1); }
    __builtin_amdgcn_sched_barrier(0);
    if (st) asm volatile("s_waitcnt vmcnt(3)" ::: "memory");
    else    asm volatile("s_waitcnt vmcnt(0)" ::: "memory");
    BAR(); MM(af,bf,1); BAR();
  }

  // ---- per-row RMS scale from head partials ----
  __syncthreads();                         // L free after main loop
  float* SS = (float*)&L[0];               // [128] rsqrt scales
  if (tid < 128){
    const float* p = ssqp + (size_t)(m0 + tid)*16;
    float s = 0.f;
#pragma unroll
    for (int h=0; h<16; ++h) s += p[h];
    SS[tid] = rsqrtf(s*(1.f/2048.f) + 1e-6f);
  }
  __syncthreads();

#pragma unroll
  for (int nf=0; nf<4; ++nf){
    const int col = n0 + wn*64 + nf*16 + c;
    const float bv = bias[col];
#pragma unroll
    for (int mf=0; mf<4; ++mf){
      const int rowl = wm*64 + mf*16 + g*4;
#pragma unroll
      for (int r=0; r<4; ++r)
        C[(size_t)(m0+rowl+r)*N + col] = acc[mf][nf][r]*SS[rowl+r] + bv;
    }
  }
}

// ---------------- causal MFMA flash attention (swapped-operand) -------------
// XCD-local mapping; epilogue also writes per-(row, head) partial sumsq of the
// normalized output into ssqp[row][h] (each cell written by exactly one lane).
__global__ __launch_bounds__(256, 2) void k_attn(const unsigned short* __restrict__ Qp,
                                                 const unsigned short* __restrict__ Kp,
                                                 const unsigned short* __restrict__ Vt,
                                                 unsigned short* __restrict__ Ar,
                                                 float* __restrict__ ssqp){
  const int L = blockIdx.x;
  const int xcdL = L & 7, j = L >> 3;
  const int bh = xcdL*4 + ((j & 31) >> 3);
  const int qtile = (j < 32) ? (8 + (j & 7)) : (7 - (j & 7));
  const int b = bh >> 4, h = bh & 15;
  const int tid = threadIdx.x;
  const int w = tid >> 6, lane = tid & 63, g = lane >> 4, c = lane & 15;
  const int r0w = qtile*128 + w*32;

  const unsigned short* Qh = Qp + (size_t)bh * Sq * DHq;
  const unsigned short* Kh = Kp + (size_t)bh * Sq * DHq;
  const unsigned short* Vh = Vt + (size_t)bh * DHq * Sq;

  __shared__ __align__(16) unsigned short Ks[2][64*128];   // 32 KB
  __shared__ __align__(16) unsigned short Vs[2][128*64];   // 32 KB
  __shared__ __align__(16) unsigned short Pl[4][32*64];    // 16 KB  (per-wave [q][k])
  unsigned short* Pw = &Pl[w][0];

  s16x8 qf[2][4];
#pragma unroll
  for (int mi=0;mi<2;mi++)
#pragma unroll
    for (int kc=0;kc<4;kc++)
      qf[mi][kc] = *(const s16x8*)&Qh[(size_t)(r0w + mi*16 + c)*DHq + kc*32 + g*8];

  f32x4 acc[2][8];
#pragma unroll
  for (int mi=0;mi<2;mi++)
#pragma unroll
    for (int dt=0;dt<8;dt++)
#pragma unroll
      for (int r=0;r<4;r++) acc[mi][dt][r] = 0.f;
  float m_r[2] = { -INFINITY, -INFINITY };
  float l_p[2] = { 0.f, 0.f };             // per-lane PARTIAL sums

  const int nsteps = 2*qtile + 2;

  auto stage = [&](int j0s, int bufi){
#pragma unroll
    for (int i=0;i<4;i++){
      int pk = tid + i*256;              // K: 1024 chunks of 16B
      int row = pk>>4, pcc = pk&15;
      gload_lds16(&Kh[(size_t)(j0s+row)*DHq + ((pcc^(row&7))<<3)], &Ks[bufi][pk*8]);
    }
#pragma unroll
    for (int i=0;i<4;i++){
      int pk = tid + i*256;              // V: 1024 chunks of 16B
      int row = pk>>3, pcc = pk&7;
      gload_lds16(&Vh[(size_t)row*Sq + j0s + ((pcc^(row&7))<<3)], &Vs[bufi][pk*8]);
    }
  };

  stage(0, 0);
  __syncthreads();

  for (int t=0; t<nsteps; ++t){
    const int j0 = t*64;
    if (t+1 < nsteps) stage((t+1)*64, (t+1)&1);

    if (j0 <= r0w + 31){
      const unsigned short* Kc = &Ks[t&1][0];
      const unsigned short* Vc = &Vs[t&1][0];

      // ---- S^T = K.Q^T ----
      f32x4 sv[2][4];
#pragma unroll
      for (int mi=0;mi<2;mi++)
#pragma unroll
        for (int js=0;js<4;js++)
#pragma unroll
          for (int r=0;r<4;r++) sv[mi][js][r] = 0.f;

      __builtin_amdgcn_s_setprio(1);
#pragma unroll
      for (int js=0;js<4;js++){
        s16x8 kf[4];
#pragma unroll
        for (int kc=0;kc<4;kc++)
          kf[kc] = *(const s16x8*)&Kc[(js*16 + c)*128 + (((kc*4+g)^(c&7))<<3)];
#pragma unroll
        for (int mi=0;mi<2;mi++)
#pragma unroll
          for (int kc=0;kc<4;kc++)
            sv[mi][js] = __builtin_amdgcn_mfma_f32_16x16x32_bf16(kf[kc], qf[mi][kc], sv[mi][js], 0,0,0);
      }
      __builtin_amdgcn_s_setprio(0);

      if (j0 + 63 > r0w){
#pragma unroll
        for (int mi=0;mi<2;mi++){
          const int q = r0w + mi*16 + c;
#pragma unroll
          for (int js=0;js<4;js++)
#pragma unroll
            for (int r=0;r<4;r++)
              if (j0 + js*16 + g*4 + r > q) sv[mi][js][r] = -INFINITY;
        }
      }

      float pmx[2];
#pragma unroll
      for (int mi=0;mi<2;mi++){
        float mx = fmaxf(fmaxf(sv[mi][0][0],sv[mi][0][1]), fmaxf(sv[mi][0][2],sv[mi][0][3]));
#pragma unroll
        for (int js=1;js<4;js++){
          float a = fmaxf(fmaxf(sv[mi][js][0],sv[mi][js][1]), fmaxf(sv[mi][js][2],sv[mi][js][3]));
          mx = fmaxf(mx, a);
        }
        mx = fmaxf(mx, __shfl_xor(mx, 16));
        mx = fmaxf(mx, __shfl_xor(mx, 32));
        pmx[mi] = mx;
      }
      int need = (pmx[0] > m_r[0] + 8.f) | (pmx[1] > m_r[1] + 8.f);
      if (__any(need)){
#pragma unroll
        for (int mi=0;mi<2;mi++){
          float mnew = fmaxf(m_r[mi], pmx[mi]);
          float corr = exp2f(m_r[mi] - mnew);
          l_p[mi] *= corr;
          m_r[mi] = mnew;
#pragma unroll
          for (int dt=0;dt<8;dt++)
#pragma unroll
            for (int r=0;r<4;r++) acc[mi][dt][r] *= corr;
        }
      }
#pragma unroll
      for (int mi=0;mi<2;mi++){
        const float mm = m_r[mi];
        const int rowoff = (mi*16 + c)*64;
#pragma unroll
        for (int js=0;js<4;js++){
          float e0 = exp2f(sv[mi][js][0] - mm);
          float e1 = exp2f(sv[mi][js][1] - mm);
          float e2 = exp2f(sv[mi][js][2] - mm);
          float e3 = exp2f(sv[mi][js][3] - mm);
          l_p[mi] += (e0+e1)+(e2+e3);
          uint2 pk2;
          pk2.x = cvtpk_bf16(e0, e1);
          pk2.y = cvtpk_bf16(e2, e3);
          const int kc8 = js*2 + (g>>1);
          *(uint2*)&Pw[rowoff + ((kc8 ^ (c&7))<<3) + (g&1)*4] = pk2;
        }
      }

      s16x8 pfr[2][2];
#pragma unroll
      for (int mi=0;mi<2;mi++)
#pragma unroll
        for (int kc=0;kc<2;kc++)
          pfr[mi][kc] = *(const s16x8*)&Pw[(mi*16 + c)*64 + (((kc*4+g)^(c&7))<<3)];
      __builtin_amdgcn_s_setprio(1);
#pragma unroll
      for (int dt=0; dt<8; dt++){
#pragma unroll
        for (int kc=0;kc<2;kc++){
          s16x8 vfr = *(const s16x8*)&Vc[(dt*16 + c)*64 + (((kc*4+g)^(c&7))<<3)];
#pragma unroll
          for (int mi=0;mi<2;mi++)
            acc[mi][dt] = __builtin_amdgcn_mfma_f32_16x16x32_bf16(vfr, pfr[mi][kc], acc[mi][dt], 0,0,0);
        }
      }
      __builtin_amdgcn_s_setprio(0);
    }
    __syncthreads();
  }

  // ---- epilogue: normalize, write O^T + per-head sumsq partial ----
#pragma unroll
  for (int mi=0;mi<2;mi++){
    float l = l_p[mi];
    l += __shfl_xor(l, 16);
    l += __shfl_xor(l, 32);
    const float inv = 1.f / l;
    const int row = r0w + mi*16 + c;
    unsigned short* dst = &Ar[((size_t)(b*Sq + row))*Dq + h*DHq];
    float sq = 0.f;
#pragma unroll
    for (int dt=0; dt<8; dt++){
      float v0 = acc[mi][dt][0]*inv, v1 = acc[mi][dt][1]*inv;
      float v2 = acc[mi][dt][2]*inv, v3 = acc[mi][dt][3]*inv;
      sq += v0*v0 + v1*v1 + v2*v2 + v3*v3;
      uint2 o2;
      o2.x = cvtpk_bf16(v0, v1);
      o2.y = cvtpk_bf16(v2, v3);
      *(uint2*)&dst[dt*16 + g*4] = o2;
    }
    sq += __shfl_xor(sq, 16);
    sq += __shfl_xor(sq, 32);
    if (g == 0)
      ssqp[(size_t)(b*Sq + row)*16 + h] = sq;
  }
}

extern "C" void kernel_launch(void* const* d_in, const int* in_sizes, int n_in,
                              void* d_out, int out_size, void* d_ws, size_t ws_size,
                              hipStream_t stream){
  const float* x     = (const float*)d_in[0];
  const float* rp    = (const float*)d_in[1];
  const float* Win   = (const float*)d_in[2];
  const float* b_in  = (const float*)d_in[3];
  const float* Wout  = (const float*)d_in[4];
  const float* b_out = (const float*)d_in[5];
  const float* qk_w  = (const float*)d_in[6];
  const float* out_w = (const float*)d_in[7];
  float* outp = (float*)d_out;

  if (ws_size < (160ull<<20)) return;   // need 160 MiB scratch

  char* ws = (char*)d_ws;
  unsigned short* Xb    = (unsigned short*)(ws);                 // 16 MiB
  unsigned short* Wb    = (unsigned short*)(ws + (16ull<<20));   // 24 MiB
  unsigned short* Woutb = (unsigned short*)(ws + (40ull<<20));   //  8 MiB
  float*          ssqp  = (float*)         (ws + (48ull<<20));   // 256 KiB
  float2*         rpcs  = (float2*)        (ws + (49ull<<20));   //  1 MiB
  unsigned short* Qp    = (unsigned short*)(ws + (96ull<<20));   // 16 MiB
  unsigned short* Kp    = (unsigned short*)(ws + (112ull<<20));  // 16 MiB
  unsigned short* Vt    = (unsigned short*)(ws + (128ull<<20));  // 16 MiB
  unsigned short* Ar    = (unsigned short*)(ws + (144ull<<20));  // 16 MiB

  // 1) fused converts (out_w folded into Woutb) + RoPE cos/sin table
  k_convert3<<<2048, 256, 0, stream>>>(x, Win, Wout, out_w, rp, Xb, Wb, Woutb, rpcs);
  // 2) QKV GEMM + fused RoPE/RMS-norm/V-transpose epilogue
  k_gemm1f<<<768, 512, 0, stream>>>(Xb, Wb, b_in, rpcs, qk_w, Qp, Kp, Vt);
  // 3) causal flash attention (XCD-local) + per-head sumsq partials
  k_attn<<<512, 256, 0, stream>>>(Qp, Kp, Vt, Ar, ssqp);
  // 4) Out = rms_scale(Ar) * (Ar . (out_w*Wout)^T) + b_out
  k_gemm2_8ph<<<256, 512, 0, stream>>>(Ar, Woutb, b_out, ssqp, outp);
}